// Round 1
// 3894.333 us; speedup vs baseline: 1.1013x; 1.1013x over previous
//
#include <hip/hip_runtime.h>
#include <math.h>

// Problem constants
#define BATCH 32
#define TIN   50
#define TOUTS 50
#define HDIM  512
#define VOC   32000
#define NBL   250          // k_logits blocks (128 v-rows each)
#define DELTA 0.0625f      // argmax candidate margin (bf16-MFMA error bound ~0.013)

// ws layout (float offsets)
#define OFF_HA    0
#define OFF_HB    16384
#define OFF_XC    32768
#define OFF_XCPRE 49152
#define OFF_ATTNX 65536
#define OFF_PM    81920      // 250*32
#define OFF_PS    97920
#define OFF_PA    113920     // int
#define OFF_LSE   129920     // 50*32
#define OFF_PM2   131584     // 250*32
#define OFF_PA2   139584     // int, 250*32

// d_out layout (float offsets)
#define OUT_HT    51200000   // B*V*TOUT
#define OUT_ATTN  51216384
// W_out bf16 fragment-swizzled copy lives at out[0 .. 8.2M floats) (32.8 MB),
// dead scratch until k_transpose overwrites it at the very end.

typedef unsigned short ushort8 __attribute__((ext_vector_type(8)));
typedef short s16x8 __attribute__((ext_vector_type(8)));
typedef float f32x16 __attribute__((ext_vector_type(16)));

static __device__ __forceinline__ unsigned short f2bf(float x) {
  unsigned int u = __float_as_uint(x);
  unsigned int r = (u + 0x7fffu + ((u >> 16) & 1u)) >> 16;
  return (unsigned short)r;
}
static __device__ __forceinline__ unsigned short f2h(float x) {
  _Float16 h = (_Float16)x;
  return __builtin_bit_cast(unsigned short, h);
}
static __device__ __forceinline__ float h2f(unsigned short u) {
  _Float16 h = __builtin_bit_cast(_Float16, u);
  return (float)h;
}
static __device__ __forceinline__ float dot4(float4 a, float4 b) {
  return a.x*b.x + a.y*b.y + a.z*b.z + a.w*b.w;
}
// top-2 insert with lower-index tie-break
static __device__ __forceinline__ void ins2(float cv, int ci, float& M1, int& A1,
                                            float& M2, int& A2) {
  if (cv > M1 || (cv == M1 && ci < A1)) { M2 = M1; A2 = A1; M1 = cv; A1 = ci; }
  else if (cv > M2 || (cv == M2 && ci < A2)) { M2 = cv; A2 = ci; }
}

// --------------------------------------------------------------- k_wconv ---
// One-time: W_out fp32 -> bf16, stored in MFMA A-fragment order:
// frag index = ((tv*32 + tk)*64 + lane), lane = (v&31) + 32*((k>>3)&1),
// 8 contiguous k per lane. Per (v-tile,k-step) a wave reads 1 KB contiguous.
__global__ __launch_bounds__(256) void k_wconv(const float* __restrict__ W_out,
                                               float* __restrict__ out) {
  int n = blockIdx.x * 256 + threadIdx.x;      // (v, k-octet), 32000*64 total
  if (n >= VOC * 64) return;
  int v = n >> 6, oct = n & 63;
  const float4* src = (const float4*)W_out + ((size_t)v * 128 + oct * 2);
  float4 x = src[0], y4 = src[1];
  ushort8 pk;
  pk[0]=f2bf(x.x);  pk[1]=f2bf(x.y);  pk[2]=f2bf(x.z);  pk[3]=f2bf(x.w);
  pk[4]=f2bf(y4.x); pk[5]=f2bf(y4.y); pk[6]=f2bf(y4.z); pk[7]=f2bf(y4.w);
  int tv = v >> 5, tk = oct >> 1, hi = oct & 1;
  int l = (v & 31) + 32 * hi;
  size_t fi = (size_t)(tv * 32 + tk) * 64 + l;
  ((ushort8*)out)[fi] = pk;
}

// ---------------------------------------------------------------- setup ----
__global__ __launch_bounds__(256) void k_setup1(const float* __restrict__ enc,
                                                float* __restrict__ ws) {
  int idx = blockIdx.x * 256 + threadIdx.x;       // 0..16383
  int b = idx >> 9, h = idx & 511;
  const float* p = enc + (size_t)b * TIN * HDIM + h;
  float s = 0.f;
  #pragma unroll 10
  for (int t = 0; t < TIN; ++t) s += p[(size_t)t * HDIM];
  (ws + OFF_ATTNX)[idx] = s;
  (ws + OFF_HA)[idx] = 0.f;
}

__global__ __launch_bounds__(256) void k_setup2(const float* __restrict__ W_comb,
                                                const float* __restrict__ b_comb,
                                                float* __restrict__ ws) {
  __shared__ float ax[HDIM];
  const int tid = threadIdx.x;
  const int b = blockIdx.x >> 1, half = blockIdx.x & 1;
  if (tid < 128)
    ((float4*)ax)[tid] = ((const float4*)(ws + OFF_ATTNX + b * HDIM))[tid];
  __syncthreads();
  int i = half * 256 + tid;
  float acc = b_comb[i];
  const float4* w4 = (const float4*)W_comb + (size_t)i * 256 + 128; // cols 512..1023
  const float4* a4 = (const float4*)ax;
  #pragma unroll 8
  for (int j = 0; j < 128; ++j) acc += dot4(w4[j], a4[j]);
  (ws + OFF_XCPRE)[b * HDIM + i] = acc;
}

// ------------------------------------------------------------------ k_xc ---
// Reduces previous step's softmax partials (max -> candidates -> exact fp32
// refine -> tok, writes lse[t-1]), then
// xc[b][i] = relu(xc_pre[b][i] + dot(emb[tok], W_comb[i][0:512])).
__global__ __launch_bounds__(256) void k_xc(const float* __restrict__ emb,
                                            const int* __restrict__ y,
                                            const float* __restrict__ W_comb,
                                            const float* __restrict__ W_out,
                                            const float* __restrict__ b_out,
                                            float* __restrict__ ws, int t) {
  __shared__ float sm[256];
  __shared__ float em[HDIM];
  __shared__ int   candv[64];
  __shared__ float candval[64];
  __shared__ int   ncand_s, tok_s;
  const int tid = threadIdx.x;
  const int b = blockIdx.x >> 1, half = blockIdx.x & 1;
  const float* pm  = ws + OFF_PM;
  const float* ps  = ws + OFF_PS;
  const float* pm2 = ws + OFF_PM2;
  const int*   pa  = (const int*)(ws + OFF_PA);
  const int*   pa2 = (const int*)(ws + OFF_PA2);
  int tok;
  if (t == 0) {
    tok = y[b * TOUTS];                       // y[:,0]
  } else {
    const bool act = tid < NBL;
    // phase 1: global max over 250 block partials
    float M = act ? pm[tid * 32 + b] : -3.4e38f;
    sm[tid] = M;
    __syncthreads();
    for (int s = 128; s > 0; s >>= 1) {
      if (tid < s) sm[tid] = fmaxf(sm[tid], sm[tid + s]);
      __syncthreads();
    }
    float Mstar = sm[0];
    __syncthreads();
    // phase 2: logsumexp
    float S = act ? ps[tid * 32 + b] * expf(pm[tid * 32 + b] - Mstar) : 0.f;
    sm[tid] = S;
    __syncthreads();
    for (int s = 128; s > 0; s >>= 1) {
      if (tid < s) sm[tid] += sm[tid + s];
      __syncthreads();
    }
    if (tid == 0 && half == 0)
      (ws + OFF_LSE)[(t - 1) * 32 + b] = Mstar + logf(sm[0]);
    // phase 3: candidate gather (anything within DELTA of the bf16-MFMA max)
    if (tid == 0) ncand_s = 0;
    __syncthreads();
    if (act) {
      float v1 = pm[tid * 32 + b];
      if (v1 >= Mstar - DELTA) {
        int s_ = atomicAdd(&ncand_s, 1);
        if (s_ < 64) candv[s_] = pa[tid * 32 + b];
      }
      float v2 = pm2[tid * 32 + b];
      if (v2 >= Mstar - DELTA) {
        int s_ = atomicAdd(&ncand_s, 1);
        if (s_ < 64) candv[s_] = pa2[tid * 32 + b];
      }
    }
    __syncthreads();
    int n = min(ncand_s, 64);
    // phase 4: exact fp32 refine, one wave per candidate
    const float* hprev = ws + ((t & 1) ? OFF_HB : OFF_HA);
    const int lane = tid & 63, wv = tid >> 6;
    for (int c = wv; c < n; c += 4) {
      int v = candv[c];
      const float4* hv  = (const float4*)(hprev + b * HDIM) + lane * 2;
      const float4* wv4 = (const float4*)(W_out + (size_t)v * HDIM) + lane * 2;
      float d = dot4(hv[0], wv4[0]) + dot4(hv[1], wv4[1]);
      #pragma unroll
      for (int m = 1; m < 64; m <<= 1) d += __shfl_xor(d, m, 64);
      if (lane == 0) candval[c] = d + b_out[v];
    }
    __syncthreads();
    if (tid == 0) {
      float bv = -3.4e38f; int bi = 0x7fffffff;
      for (int c = 0; c < n; ++c) {
        int v = candv[c]; float x = candval[c];
        if (x > bv || (x == bv && v < bi)) { bv = x; bi = v; }
      }
      tok_s = bi;
    }
    __syncthreads();
    tok = tok_s;
  }
  // stage emb row
  if (tid < 128)
    ((float4*)em)[tid] = ((const float4*)(emb + (size_t)tok * HDIM))[tid];
  __syncthreads();
  int i = half * 256 + tid;
  float acc = (ws + OFF_XCPRE)[b * HDIM + i];
  const float4* w4 = (const float4*)W_comb + (size_t)i * 256;   // cols 0..511
  const float4* e4 = (const float4*)em;
  #pragma unroll 8
  for (int j = 0; j < 128; ++j) acc += dot4(w4[j], e4[j]);
  (ws + OFF_XC)[b * HDIM + i] = fmaxf(acc, 0.f);
}

// ----------------------------------------------------------------- k_gru ---
__global__ __launch_bounds__(256) void k_gru(const float* __restrict__ W_ih,
                                             const float* __restrict__ W_hh,
                                             const float* __restrict__ b_ih,
                                             const float* __restrict__ b_hh,
                                             float* __restrict__ ws, int t) {
  __shared__ float xcs[8 * 516];
  __shared__ float hs [8 * 516];
  __shared__ float red[4 * 64 * 6];
  const int tid = threadIdx.x;
  const int btile = blockIdx.x & 3;
  const int itile = blockIdx.x >> 2;            // 0..63
  const int b0 = btile * 8, i0 = itile * 8;
  const float* hb_in  = ws + ((t & 1) ? OFF_HB : OFF_HA);
  float*       hb_out = ws + ((t & 1) ? OFF_HA : OFF_HB);
  const float4* xcg = (const float4*)(ws + OFF_XC);
  const float4* hg  = (const float4*)hb_in;
  #pragma unroll
  for (int q = 0; q < 4; ++q) {
    int pos = q * 256 + tid;                    // f4 idx 0..1023
    int bl = pos >> 7, j = pos & 127;
    ((float4*)xcs)[bl * 129 + j] = xcg[(size_t)(b0 + bl) * 128 + j];
    ((float4*)hs )[bl * 129 + j] = hg [(size_t)(b0 + bl) * 128 + j];
  }
  __syncthreads();
  const int pair = tid >> 2, kh = tid & 3;      // pair 0..63
  const int bl = pair >> 3, il = pair & 7;
  const int i = i0 + il;
  float a0 = 0, a1 = 0, a2 = 0, a3 = 0, a4 = 0, a5 = 0;
  const float4* wi0 = (const float4*)(W_ih + (size_t)(i       ) * HDIM);
  const float4* wi1 = (const float4*)(W_ih + (size_t)(i +  512) * HDIM);
  const float4* wi2 = (const float4*)(W_ih + (size_t)(i + 1024) * HDIM);
  const float4* wh0 = (const float4*)(W_hh + (size_t)(i       ) * HDIM);
  const float4* wh1 = (const float4*)(W_hh + (size_t)(i +  512) * HDIM);
  const float4* wh2 = (const float4*)(W_hh + (size_t)(i + 1024) * HDIM);
  const float4* xv4 = (const float4*)xcs + bl * 129;
  const float4* hv4 = (const float4*)hs  + bl * 129;
  #pragma unroll 4
  for (int j = 0; j < 32; ++j) {
    int f4 = kh + 4 * j;                        // strided -> 64B-coalesced W
    float4 xv = xv4[f4], hv = hv4[f4];
    a0 += dot4(wi0[f4], xv);
    a1 += dot4(wi1[f4], xv);
    a2 += dot4(wi2[f4], xv);
    a3 += dot4(wh0[f4], hv);
    a4 += dot4(wh1[f4], hv);
    a5 += dot4(wh2[f4], hv);
  }
  float* rp = red + (kh * 64 + pair) * 6;
  rp[0] = a0; rp[1] = a1; rp[2] = a2; rp[3] = a3; rp[4] = a4; rp[5] = a5;
  __syncthreads();
  if (tid < 64) {
    const float* r0 = red + (0 * 64 + tid) * 6;
    const float* r1 = red + (1 * 64 + tid) * 6;
    const float* r2 = red + (2 * 64 + tid) * 6;
    const float* r3 = red + (3 * 64 + tid) * 6;
    int bl2 = tid >> 3, il2 = tid & 7;
    int ii = i0 + il2;
    float gir = r0[0] + r1[0] + r2[0] + r3[0] + b_ih[ii];
    float giz = r0[1] + r1[1] + r2[1] + r3[1] + b_ih[ii + 512];
    float gin = r0[2] + r1[2] + r2[2] + r3[2] + b_ih[ii + 1024];
    float ghr = r0[3] + r1[3] + r2[3] + r3[3] + b_hh[ii];
    float ghz = r0[4] + r1[4] + r2[4] + r3[4] + b_hh[ii + 512];
    float ghn = r0[5] + r1[5] + r2[5] + r3[5] + b_hh[ii + 1024];
    float r = 1.f / (1.f + expf(-(gir + ghr)));
    float z = 1.f / (1.f + expf(-(giz + ghz)));
    float n = tanhf(gin + r * ghn);
    float hold = hs[bl2 * 516 + ii];
    hb_out[(b0 + bl2) * HDIM + ii] = (1.f - z) * n + z * hold;
  }
}

// -------------------------------------------------------------- k_logits ---
// logits[b][v] = h . W_out[v] + b_out[v] via bf16 MFMA 32x32x16.
// 250 blocks x 256 threads (4 waves); each wave owns one 32-v tile (128 v/blk).
// Emits per-(block,b) top-2 + expsum partials and fp16 logits into attn region.
__global__ __launch_bounds__(256) void k_logits(const float* __restrict__ b_out,
                                                float* __restrict__ ws,
                                                float* __restrict__ out, int t) {
  __shared__ unsigned short h_lds[16384];       // 32 KB: bf16 h B-fragments
  __shared__ unsigned short lout[32 * 136];     // fp16 logits [b][128v], padded
  __shared__ float wm1[128], wm2[128], wss[128];
  __shared__ int   wa1[128], wa2[128];
  const int tid = threadIdx.x, blk = blockIdx.x;
  const int lane = tid & 63, w = tid >> 6;
  const float* hb = ws + (((t + 1) & 1) ? OFF_HB : OFF_HA);
  // stage h fp32 -> bf16 fragment order: frag(oct,b) at h_lds[(oct*32+b)*8]
  {
    const float4* h4 = (const float4*)hb;
    int bb = tid >> 3, og = tid & 7;
    #pragma unroll
    for (int jo = 0; jo < 8; ++jo) {
      int oct = og * 8 + jo;
      float4 x  = h4[bb * 128 + oct * 2];
      float4 y4 = h4[bb * 128 + oct * 2 + 1];
      ushort8 pk;
      pk[0]=f2bf(x.x);  pk[1]=f2bf(x.y);  pk[2]=f2bf(x.z);  pk[3]=f2bf(x.w);
      pk[4]=f2bf(y4.x); pk[5]=f2bf(y4.y); pk[6]=f2bf(y4.z); pk[7]=f2bf(y4.w);
      *(ushort8*)&h_lds[((size_t)oct * 32 + bb) * 8] = pk;
    }
  }
  __syncthreads();
  f32x16 acc;
  #pragma unroll
  for (int r = 0; r < 16; ++r) acc[r] = 0.f;
  const s16x8* wp = (const s16x8*)out + (size_t)(blk * 4 + w) * 2048 + lane;
  const s16x8* hp = (const s16x8*)h_lds + lane;
  #pragma unroll 8
  for (int ks = 0; ks < 32; ++ks) {
    s16x8 a  = wp[ks * 64];                     // 1 KB/wave contiguous
    s16x8 bf = hp[ks * 64];                     // conflict-free ds_read_b128
    acc = __builtin_amdgcn_mfma_f32_32x32x16_bf16(a, bf, acc, 0, 0, 0);
  }
  // epilogue: C[v][b], col=lane&31, row=(r&3)+8*(r>>2)+4*(lane>>5)
  const int b = lane & 31, hi = lane >> 5;
  const int vb = blk * 128 + w * 32;
  float vals[16];
  float m1 = -3.4e38f, m2 = -3.4e38f; int a1 = -1, a2 = -1;
  #pragma unroll
  for (int r = 0; r < 16; ++r) {
    int row = (r & 3) + 8 * (r >> 2) + 4 * hi;
    int v = vb + row;
    float x = acc[r] + b_out[v];
    vals[r] = x;
    ins2(x, v, m1, a1, m2, a2);
  }
  float s = 0.f;
  #pragma unroll
  for (int r = 0; r < 16; ++r) s += expf(vals[r] - m1);
  #pragma unroll
  for (int r = 0; r < 16; ++r) {
    int row = (r & 3) + 8 * (r >> 2) + 4 * hi;
    lout[b * 136 + w * 32 + row] = f2h(vals[r]);
  }
  // merge with partner lane (lane^32 has the same col, other 16 rows)
  float o1 = __shfl_xor(m1, 32, 64); int oa1 = __shfl_xor(a1, 32, 64);
  float o2 = __shfl_xor(m2, 32, 64); int oa2 = __shfl_xor(a2, 32, 64);
  float os = __shfl_xor(s, 32, 64);
  float M1 = m1, M2 = m2; int A1 = a1, A2 = a2;
  ins2(o1, oa1, M1, A1, M2, A2);
  ins2(o2, oa2, M1, A1, M2, A2);
  float S = s * expf(m1 - M1) + os * expf(o1 - M1);
  if (lane < 32) {
    wm1[w * 32 + b] = M1; wm2[w * 32 + b] = M2; wss[w * 32 + b] = S;
    wa1[w * 32 + b] = A1; wa2[w * 32 + b] = A2;
  }
  __syncthreads();
  if (tid < 32) {                               // per-b merge across 4 waves
    float BM1 = -3.4e38f, BM2 = -3.4e38f; int BA1 = -1, BA2 = -1;
    #pragma unroll
    for (int q = 0; q < 4; ++q) {
      ins2(wm1[q * 32 + tid], wa1[q * 32 + tid], BM1, BA1, BM2, BA2);
      ins2(wm2[q * 32 + tid], wa2[q * 32 + tid], BM1, BA1, BM2, BA2);
    }
    float BS = 0.f;
    #pragma unroll
    for (int q = 0; q < 4; ++q) BS += wss[q * 32 + tid] * expf(wm1[q * 32 + tid] - BM1);
    (ws + OFF_PM )[blk * 32 + tid] = BM1;
    (ws + OFF_PS )[blk * 32 + tid] = BS;
    (ws + OFF_PM2)[blk * 32 + tid] = BM2;
    ((int*)(ws + OFF_PA ))[blk * 32 + tid] = BA1;
    ((int*)(ws + OFF_PA2))[blk * 32 + tid] = BA2;
  }
  // store fp16 logits (coalesced 32 B/thread) into attn scratch
  {
    int bb = tid >> 3, vg = tid & 7;
    ushort8 u0 = *(const ushort8*)&lout[bb * 136 + vg * 16];
    ushort8 u1 = *(const ushort8*)&lout[bb * 136 + vg * 16 + 8];
    unsigned short* lb = (unsigned short*)(out + OUT_ATTN);
    unsigned short* dst = lb + ((size_t)t * 32 + bb) * VOC + blk * 128 + vg * 16;
    *(ushort8*)dst = u0;
    *(ushort8*)(dst + 8) = u1;
  }
}

// ---------------------------------------------------------------- k_last ---
__global__ __launch_bounds__(256) void k_last(float* __restrict__ ws,
                                              float* __restrict__ out) {
  __shared__ float sm[256];
  const int tid = threadIdx.x, blk = blockIdx.x;
  out[OUT_HT + blk * 256 + tid] = (ws + OFF_HA)[blk * 256 + tid]; // h_50 in buf A
  if (blk >= 32) return;
  const int b = blk;
  const float* pm = ws + OFF_PM;
  const float* ps = ws + OFF_PS;
  float M = (tid < NBL) ? pm[tid * 32 + b] : -3.4e38f;
  sm[tid] = M; __syncthreads();
  for (int s = 128; s > 0; s >>= 1) { if (tid < s) sm[tid] = fmaxf(sm[tid], sm[tid + s]); __syncthreads(); }
  float Mstar = sm[0]; __syncthreads();
  float S = (tid < NBL) ? ps[tid * 32 + b] * expf(pm[tid * 32 + b] - Mstar) : 0.f;
  sm[tid] = S; __syncthreads();
  for (int s = 128; s > 0; s >>= 1) { if (tid < s) sm[tid] += sm[tid + s]; __syncthreads(); }
  if (tid == 0) (ws + OFF_LSE)[49 * 32 + b] = Mstar + logf(sm[0]);
}

// ----------------------------------------------------------- k_transpose ---
// out[b][v][t] = fp16_logits[t][b][v] - lse[t][b].  LDS-tiled, coalesced.
__global__ __launch_bounds__(256) void k_transpose(const float* __restrict__ ws,
                                                   float* __restrict__ out) {
  __shared__ float lds[50 * 257];
  const int tid = threadIdx.x;
  int blk = blockIdx.x;
  int b = blk / 125, vt = blk % 125;
  int v0 = vt * 256;
  const unsigned short* lb = (const unsigned short*)(out + OUT_ATTN);
  const float* lse = ws + OFF_LSE;
  for (int tt = 0; tt < TOUTS; ++tt) {
    unsigned short us = lb[((size_t)tt * 32 + b) * VOC + v0 + tid];
    lds[tt * 257 + tid] = h2f(us) - lse[tt * 32 + b];
  }
  __syncthreads();
  float* ob = out + ((size_t)b * VOC + v0) * TOUTS;
  for (int j = 0; j < 50; ++j) {
    int flat = j * 256 + tid;
    int vloc = flat / 50, tt = flat - vloc * 50;
    ob[flat] = lds[tt * 257 + vloc];
  }
}

// ---------------------------------------------------------------- k_fill ---
__global__ void k_fill(float* __restrict__ out) {
  float4* a4 = (float4*)(out + OUT_ATTN);
  unsigned int idx = blockIdx.x * 256 + threadIdx.x;
  float4 one = make_float4(1.f, 1.f, 1.f, 1.f);
  for (size_t i = idx; i < 10240000u; i += (size_t)4096 * 256) a4[i] = one;
}

// ---------------------------------------------------------------- launch ---
extern "C" void kernel_launch(void* const* d_in, const int* in_sizes, int n_in,
                              void* d_out, int out_size, void* d_ws, size_t ws_size,
                              hipStream_t stream) {
  (void)in_sizes; (void)n_in; (void)out_size; (void)ws_size;
  const float* enc    = (const float*)d_in[0];
  const int*   y      = (const int*)  d_in[1];
  const float* emb    = (const float*)d_in[2];
  // d_in[3..6]: W_fc, b_fc, W_fc1, W_fc2 -- dead code (softmax over size-1 axis == 1)
  const float* W_comb = (const float*)d_in[7];
  const float* b_comb = (const float*)d_in[8];
  const float* W_ih   = (const float*)d_in[9];
  const float* W_hh   = (const float*)d_in[10];
  const float* b_ih   = (const float*)d_in[11];
  const float* b_hh   = (const float*)d_in[12];
  const float* W_out  = (const float*)d_in[13];
  const float* b_out  = (const float*)d_in[14];
  float* out = (float*)d_out;
  float* ws  = (float*)d_ws;

  k_wconv <<<8000, 256, 0, stream>>>(W_out, out);   // bf16 fragment-swizzled W
  k_setup1<<<64,   256, 0, stream>>>(enc, ws);
  k_setup2<<<64,   256, 0, stream>>>(W_comb, b_comb, ws);
  for (int t = 0; t < TOUTS; ++t) {
    k_xc    <<<64,  256, 0, stream>>>(emb, y, W_comb, W_out, b_out, ws, t);
    k_gru   <<<256, 256, 0, stream>>>(W_ih, W_hh, b_ih, b_hh, ws, t);
    k_logits<<<NBL, 256, 0, stream>>>(b_out, ws, out, t);
  }
  k_last     <<<64,   256, 0, stream>>>(ws, out);
  k_transpose<<<4000, 256, 0, stream>>>(ws, out);
  k_fill     <<<4096, 256, 0, stream>>>(out);
}